// Round 4
// baseline (780.911 us; speedup 1.0000x reference)
//
#include <hip/hip_runtime.h>
#include <math.h>

typedef unsigned short u16;
typedef __bf16 bf16_t;
typedef u16 u16x4 __attribute__((ext_vector_type(4)));
typedef u16 u16x8 __attribute__((ext_vector_type(8)));
typedef bf16_t bf16x8 __attribute__((ext_vector_type(8)));
typedef float f32x4 __attribute__((ext_vector_type(4)));

__device__ __forceinline__ float bf2f(u16 v) {
    union { unsigned u; float f; } x; x.u = ((unsigned)v) << 16; return x.f;
}
__device__ __forceinline__ u16 f2bf(float f) {
    union { float f; unsigned u; } x; x.f = f;
    unsigned u = x.u;
    return (u16)((u + 0x7fffu + ((u >> 16) & 1u)) >> 16);
}

// async global->LDS, 16B per lane; LDS dest is wave-uniform base + lane*16
__device__ __forceinline__ void glds16(const u16* g, u16* l) {
    __builtin_amdgcn_global_load_lds(
        (const __attribute__((address_space(1))) void*)g,
        (__attribute__((address_space(3))) void*)l, 16, 0, 0);
}

// ---------------------------------------------------------------------------
// Runtime dtype detector (probe = Wq). bf16: high byte of each u32 is sign/exp
// in [0x38,0x3F]; fp32: uniform mantissa byte. 64-lane majority => exact.
// ---------------------------------------------------------------------------
__device__ __forceinline__ bool is_bf16_input(const unsigned* __restrict__ probe) {
    unsigned w = probe[(threadIdx.x & 63) * 32771 + 7];
    unsigned b7 = (w >> 8) & 0x7f;
    bool hit = (b7 >= 0x38) && (b7 <= 0x3f);
    return __builtin_popcountll(__ballot(hit)) >= 32;
}

__global__ __launch_bounds__(256) void convert_kernel(
    const void* __restrict__ src, u16* __restrict__ dst, int n,
    const unsigned* __restrict__ probe)
{
    bool bf = is_bf16_input(probe);
    int i = (blockIdx.x * 256 + threadIdx.x) * 8;
    if (i >= n) return;
    if (bf) {
        *(u16x8*)&dst[i] = *(const u16x8*)&((const u16*)src)[i];
    } else {
        const float* s = (const float*)src + i;
        u16x8 o;
#pragma unroll
        for (int j = 0; j < 8; j++) o[j] = f2bf(s[j]);
        *(u16x8*)&dst[i] = o;
    }
}

// all 4 biases in one launch (grid=3, flat 5120 elems; 8-chunks don't straddle)
__global__ __launch_bounds__(256) void convert_biases_kernel(
    const void* bq, const void* bk, const void* bv, const void* bo,
    u16* dq, u16* dk, u16* dv, u16* dob, const unsigned* __restrict__ probe)
{
    bool bf = is_bf16_input(probe);
    int i = (blockIdx.x * 256 + threadIdx.x) * 8;
    const void* s; u16* d; int off;
    if (i < 2048)      { s = bq; d = dq;  off = i; }
    else if (i < 2560) { s = bk; d = dk;  off = i - 2048; }
    else if (i < 3072) { s = bv; d = dv;  off = i - 2560; }
    else if (i < 5120) { s = bo; d = dob; off = i - 3072; }
    else return;
    if (bf) {
        *(u16x8*)&d[off] = *(const u16x8*)&((const u16*)s)[off];
    } else {
        const float* sf = (const float*)s + off;
        u16x8 o;
#pragma unroll
        for (int j = 0; j < 8; j++) o[j] = f2bf(sf[j]);
        *(u16x8*)&d[off] = o;
    }
}

__global__ __launch_bounds__(256) void tconv_kernel(
    const void* __restrict__ in, u16* __restrict__ out, int R, int C,
    const unsigned* __restrict__ probe)
{
    bool bf = is_bf16_input(probe);
    __shared__ u16 t[32][33];
    int x = threadIdx.x & 31, y = threadIdx.x >> 5;
    int bx = blockIdx.x * 32, by = blockIdx.y * 32;
    if (bf) {
        const u16* s = (const u16*)in;
#pragma unroll
        for (int i = 0; i < 32; i += 8)
            t[y + i][x] = s[(size_t)(by + y + i) * C + bx + x];
    } else {
        const float* s = (const float*)in;
#pragma unroll
        for (int i = 0; i < 32; i += 8)
            t[y + i][x] = f2bf(s[(size_t)(by + y + i) * C + bx + x]);
    }
    __syncthreads();
#pragma unroll
    for (int i = 0; i < 32; i += 8)
        out[(size_t)(bx + y + i) * R + by + x] = t[x][y + i];
}

__global__ __launch_bounds__(256) void transpose_kernel(
    const u16* __restrict__ in, u16* __restrict__ out, int R, int C)
{
    __shared__ u16 t[32][33];
    int x = threadIdx.x & 31, y = threadIdx.x >> 5;
    int bx = blockIdx.x * 32, by = blockIdx.y * 32;
#pragma unroll
    for (int i = 0; i < 32; i += 8)
        t[y + i][x] = in[(size_t)(by + y + i) * C + bx + x];
    __syncthreads();
#pragma unroll
    for (int i = 0; i < 32; i += 8)
        out[(size_t)(bx + y + i) * R + by + x] = t[x][y + i];
}

// ---------------------------------------------------------------------------
// GEMM (m97 structure): C[M,N] = A[M,K] @ BT[N,K]^T + bias[N]
// LDS fragment-major [kq 0..3][row 0..127] x 8 u16 — written by
// global_load_lds width=16 (wave w stages kq=w), read as ds_read_b128 with
// only 2-way bank aliasing (free). 128x128 tile, BK=32, 4 waves 2x2.
// ---------------------------------------------------------------------------
__global__ __launch_bounds__(256) void gemm_bias_kernel(
    const u16* __restrict__ A, const u16* __restrict__ BT,
    const u16* __restrict__ bias, void* __restrict__ Cout,
    int M, int N, int K, const unsigned* __restrict__ probe)
{
    __shared__ __align__(16) u16 As[128 * 32];   // 8 KB, fragment-major
    __shared__ __align__(16) u16 Bs[128 * 32];
    const int tid  = threadIdx.x;
    const int lane = tid & 63, wave = tid >> 6;
    const int quad = lane >> 4, li = lane & 15;
    const int bm = blockIdx.x * 128, bn = blockIdx.y * 128;
    const int wm = (wave >> 1) * 64, wn = (wave & 1) * 64;

    f32x4 acc[4][4] = {};

    const u16* Abase = &A [(size_t)(bm + lane) * K + wave * 8];
    const u16* Bbase = &BT[(size_t)(bn + lane) * K + wave * 8];
    u16* AsW = &As[(wave * 128) * 8];          // wave-uniform LDS bases
    u16* BsW = &Bs[(wave * 128) * 8];

    for (int k0 = 0; k0 < K; k0 += 32) {
        glds16(Abase + k0,                 AsW);
        glds16(Abase + k0 + (size_t)64 * K, AsW + 64 * 8);
        glds16(Bbase + k0,                 BsW);
        glds16(Bbase + k0 + (size_t)64 * K, BsW + 64 * 8);
        __syncthreads();
        bf16x8 af[4], bfr[4];
#pragma unroll
        for (int i = 0; i < 4; i++)
            af[i]  = *(const bf16x8*)&As[(quad * 128 + wm + i * 16 + li) * 8];
#pragma unroll
        for (int i = 0; i < 4; i++)
            bfr[i] = *(const bf16x8*)&Bs[(quad * 128 + wn + i * 16 + li) * 8];
#pragma unroll
        for (int mt = 0; mt < 4; mt++)
#pragma unroll
            for (int nt = 0; nt < 4; nt++)
                acc[mt][nt] = __builtin_amdgcn_mfma_f32_16x16x32_bf16(
                    af[mt], bfr[nt], acc[mt][nt], 0, 0, 0);
        __syncthreads();
    }

    bool bf = probe ? is_bf16_input(probe) : true;
    if (bf) {
        u16* C16 = (u16*)Cout;
#pragma unroll
        for (int nt = 0; nt < 4; nt++) {
            int col = bn + wn + nt * 16 + li;
            float bb = bf2f(bias[col]);
#pragma unroll
            for (int mt = 0; mt < 4; mt++)
#pragma unroll
                for (int r = 0; r < 4; r++) {
                    int row = bm + wm + mt * 16 + quad * 4 + r;
                    C16[(size_t)row * N + col] = f2bf(acc[mt][nt][r] + bb);
                }
        }
    } else {
        float* Cf = (float*)Cout;
#pragma unroll
        for (int nt = 0; nt < 4; nt++) {
            int col = bn + wn + nt * 16 + li;
            float bb = bf2f(bias[col]);
#pragma unroll
            for (int mt = 0; mt < 4; mt++)
#pragma unroll
                for (int r = 0; r < 4; r++) {
                    int row = bm + wm + mt * 16 + quad * 4 + r;
                    Cf[(size_t)row * N + col] = acc[mt][nt][r] + bb;
                }
        }
    }
}

// ---------------------------------------------------------------------------
// Flash attention v4: split-K (2 chunks per q-tile) + LPT ordering.
// Grid (32, H, B): x -> qt = 15-(x>>1) [heavy first], split = x&1.
// Chunk writes normalized partial O (bf16) + per-row (m,l) fp32.
// Wave = 32 q-rows; transposed-score trick; 4 blocks/CU co-resident.
// ---------------------------------------------------------------------------
__global__ __launch_bounds__(256, 4) void flash_kernel(
    const u16* __restrict__ Q, const u16* __restrict__ Kg,
    const u16* __restrict__ VT,
    u16* __restrict__ OA, u16* __restrict__ OB,
    float2* __restrict__ mlA, float2* __restrict__ mlB)
{
    constexpr int S = 2048, D = 2048, DH = 128, KVC = 512;
    constexpr float SCALE = 0.08838834764831845f;  // 1/sqrt(128)
    __shared__ __align__(16) u16 Ks[32 * 136];
    __shared__ __align__(16) u16 Vt[128 * 40];
    __shared__ __align__(16) u16 Pw[4][32 * 40];

    const int tid  = threadIdx.x;
    const int wave = tid >> 6, lane = tid & 63;
    const int quad = lane >> 4, li = lane & 15;
    const int xi = blockIdx.x, h = blockIdx.y, b = blockIdx.z;
    const int qt = 15 - (xi >> 1);
    const int split = xi & 1;
    const int g = h >> 2;
    const int q0w = qt * 128 + wave * 32;

    const int half = 2 * (qt + 1);                 // tiles in chunk A
    const int kc0 = split ? half * 32 : 0;
    const int kc1 = split ? 4 * (qt + 1) * 32 : half * 32;
    u16*    Op  = split ? OB : OA;
    float2* mlp = split ? mlB : mlA;

    const u16* Qb = Q  + (size_t)b * S * D;
    const u16* Kb = Kg + (size_t)b * S * KVC;
    const u16* Vg = VT + (size_t)g * DH * (2 * S) + (size_t)b * S;

    bf16x8 qf[2][4];
#pragma unroll
    for (int m = 0; m < 2; m++)
#pragma unroll
        for (int c = 0; c < 4; c++)
            qf[m][c] = *(const bf16x8*)&Qb[(size_t)(q0w + m * 16 + li) * D
                                           + h * DH + c * 32 + quad * 8];

    f32x4 oacc[2][8] = {};
    float mr[2] = { -INFINITY, -INFINITY };
    float lr[2] = { 0.f, 0.f };

    u16x8 kreg[2], vreg[2];
#pragma unroll
    for (int ch = 0; ch < 2; ch++) {
        int idx = tid + ch * 256;
        kreg[ch] = *(const u16x8*)&Kb[(size_t)(kc0 + (idx >> 4)) * KVC + g * DH + (idx & 15) * 8];
        vreg[ch] = *(const u16x8*)&Vg[(size_t)(idx >> 2) * (2 * S) + kc0 + (idx & 3) * 8];
    }

    for (int kc = kc0; kc < kc1; kc += 32) {
#pragma unroll
        for (int ch = 0; ch < 2; ch++) {
            int idx = tid + ch * 256;
            *(u16x8*)&Ks[(idx >> 4) * 136 + (idx & 15) * 8] = kreg[ch];
            *(u16x8*)&Vt[(idx >> 2) * 40  + (idx & 3) * 8]  = vreg[ch];
        }
        __syncthreads();

        int kn = kc + 32;
        if (kn < kc1) {
#pragma unroll
            for (int ch = 0; ch < 2; ch++) {
                int idx = tid + ch * 256;
                kreg[ch] = *(const u16x8*)&Kb[(size_t)(kn + (idx >> 4)) * KVC
                                              + g * DH + (idx & 15) * 8];
                vreg[ch] = *(const u16x8*)&Vg[(size_t)(idx >> 2) * (2 * S)
                                              + kn + (idx & 3) * 8];
            }
        }

        if (kc <= q0w) {
            f32x4 sacc[2][2] = {};
#pragma unroll
            for (int t = 0; t < 2; t++)
#pragma unroll
                for (int c = 0; c < 4; c++) {
                    bf16x8 kf = *(const bf16x8*)&Ks[(t * 16 + li) * 136 + c * 32 + quad * 8];
#pragma unroll
                    for (int m = 0; m < 2; m++)
                        sacc[m][t] = __builtin_amdgcn_mfma_f32_16x16x32_bf16(
                            kf, qf[m][c], sacc[m][t], 0, 0, 0);
                }

            float alpha_b[2][4];
#pragma unroll
            for (int m = 0; m < 2; m++) {
                int row = q0w + m * 16 + li;
                f32x4 s0 = sacc[m][0] * SCALE;
                f32x4 s1 = sacc[m][1] * SCALE;
#pragma unroll
                for (int r = 0; r < 4; r++) {
                    int k0 = kc + quad * 4 + r;
                    if (k0 > row)      s0[r] = -INFINITY;
                    if (k0 + 16 > row) s1[r] = -INFINITY;
                }
                float mx = fmaxf(fmaxf(fmaxf(s0[0], s0[1]), fmaxf(s0[2], s0[3])),
                                 fmaxf(fmaxf(s1[0], s1[1]), fmaxf(s1[2], s1[3])));
                mx = fmaxf(mx, __shfl_xor(mx, 16));
                mx = fmaxf(mx, __shfl_xor(mx, 32));
                float mnew = fmaxf(mr[m], mx);
                float al = __expf(mr[m] - mnew);
                mr[m] = mnew;
                f32x4 p0, p1;
                float ps = 0.f;
#pragma unroll
                for (int r = 0; r < 4; r++) {
                    p0[r] = __expf(s0[r] - mnew);
                    p1[r] = __expf(s1[r] - mnew);
                    ps += p0[r] + p1[r];
                }
                ps += __shfl_xor(ps, 16);
                ps += __shfl_xor(ps, 32);
                lr[m] = lr[m] * al + ps;
                u16x4 c0, c1;
#pragma unroll
                for (int r = 0; r < 4; r++) { c0[r] = f2bf(p0[r]); c1[r] = f2bf(p1[r]); }
                *(u16x4*)&Pw[wave][(m * 16 + li) * 40 + quad * 4]      = c0;
                *(u16x4*)&Pw[wave][(m * 16 + li) * 40 + 16 + quad * 4] = c1;
#pragma unroll
                for (int r = 0; r < 4; r++)
                    alpha_b[m][r] = __shfl(al, quad * 4 + r, 16);
            }

#pragma unroll
            for (int m = 0; m < 2; m++)
#pragma unroll
                for (int dt = 0; dt < 8; dt++)
#pragma unroll
                    for (int r = 0; r < 4; r++)
                        oacc[m][dt][r] *= alpha_b[m][r];

            asm volatile("s_waitcnt lgkmcnt(0)" ::: "memory");
            union { u16x8 u; bf16x8 bv; } pc0, pc1;
            pc0.u = *(const u16x8*)&Pw[wave][(0 * 16 + li) * 40 + quad * 8];
            pc1.u = *(const u16x8*)&Pw[wave][(1 * 16 + li) * 40 + quad * 8];
            bf16x8 pf[2] = { pc0.bv, pc1.bv };

#pragma unroll
            for (int dt = 0; dt < 8; dt++) {
                bf16x8 vf = *(const bf16x8*)&Vt[(dt * 16 + li) * 40 + quad * 8];
#pragma unroll
                for (int m = 0; m < 2; m++)
                    oacc[m][dt] = __builtin_amdgcn_mfma_f32_16x16x32_bf16(
                        pf[m], vf, oacc[m][dt], 0, 0, 0);
            }
        }
        __syncthreads();
    }

    // per-row (m,l) — quad 0 holds rows q0w + m*16 + li (all quads identical)
    if (lane < 16) {
#pragma unroll
        for (int m = 0; m < 2; m++) {
            int srow = q0w + m * 16 + li;
            mlp[(size_t)(b * 16 + h) * 2048 + srow] = make_float2(mr[m], lr[m]);
        }
    }

    u16* Ob = Op + (size_t)b * S * D;
#pragma unroll
    for (int m = 0; m < 2; m++) {
#pragma unroll
        for (int r = 0; r < 4; r++) {
            float l = __shfl(lr[m], quad * 4 + r, 16);
            float linv = (l > 0.f) ? 1.0f / l : 0.f;
            int row = q0w + m * 16 + quad * 4 + r;
#pragma unroll
            for (int dt = 0; dt < 8; dt++)
                Ob[(size_t)row * D + h * DH + dt * 16 + li] = f2bf(oacc[m][dt][r] * linv);
        }
    }
}

// ---------------------------------------------------------------------------
// Merge the two split-K partials (in-place into OB)
// ---------------------------------------------------------------------------
__global__ __launch_bounds__(256) void combine_kernel(
    const u16* __restrict__ OA, u16* __restrict__ OB,
    const float2* __restrict__ mlA, const float2* __restrict__ mlB)
{
    int e = (blockIdx.x * 256 + threadIdx.x) * 8;
    int row = e >> 11, col = e & 2047;
    int b = row >> 11, srow = row & 2047, h = col >> 7;
    size_t mi = (size_t)(b * 16 + h) * 2048 + srow;
    float2 a = mlA[mi], c = mlB[mi];
    float M  = fmaxf(a.x, c.x);
    float wA = a.y * __expf(a.x - M);
    float wB = c.y * __expf(c.x - M);
    float inv = 1.0f / (wA + wB);
    wA *= inv; wB *= inv;
    u16x8 va = *(const u16x8*)&OA[e];
    u16x8 vb = *(const u16x8*)&OB[e];
    u16x8 o;
#pragma unroll
    for (int j = 0; j < 8; j++)
        o[j] = f2bf(wA * bf2f(va[j]) + wB * bf2f(vb[j]));
    *(u16x8*)&OB[e] = o;
}

// ---------------------------------------------------------------------------
extern "C" void kernel_launch(void* const* d_in, const int* in_sizes, int n_in,
                              void* d_out, int out_size, void* d_ws, size_t ws_size,
                              hipStream_t stream)
{
    const void* X  = d_in[0];
    const void* Wq = d_in[3];
    const void* bq = d_in[4];
    const void* Wk = d_in[5];
    const void* bk = d_in[6];
    const void* Wv = d_in[7];
    const void* bv = d_in[8];
    const void* Wo = d_in[9];
    const void* bo = d_in[10];
    const unsigned* probe = (const unsigned*)d_in[3];

    u16* ws  = (u16*)d_ws;
    u16* Xc  = ws;                   // [4096][2048]; after QKV GEMMs reused as OA
    u16* WT  = Xc  + 8388608;        // [2048][2048] WqT, later WoT
    u16* WkT = WT  + 4194304;        // [512][2048]; after K-GEMM reused as mlA
    u16* WvT = WkT + 1048576;        // [512][2048]; after V-GEMM reused as mlB
    u16* bqc = WvT + 1048576;        // 2048
    u16* bkc = bqc + 2048;           // 512
    u16* bvc = bkc + 512;            // 512
    u16* boc = bvc + 512;            // 2048
    u16* Qb  = boc + 2048;           // [4096][2048]
    u16* Kb  = Qb  + 8388608;        // [4096][512]
    u16* Vb  = Kb  + 2097152;        // [4096][512]
    u16* VTb = Vb  + 2097152;        // [512][4096]
    u16* Ob  = VTb + 2097152;        // [4096][2048]

    u16* OA = Xc;                    // chunk-A partial O (overlay, safe: stream order)
    float2* mlA = (float2*)WkT;
    float2* mlB = (float2*)WvT;

    convert_kernel<<<4096, 256, 0, stream>>>(X, Xc, 8388608, probe);
    convert_biases_kernel<<<3, 256, 0, stream>>>(bq, bk, bv, bo, bqc, bkc, bvc, boc, probe);

    tconv_kernel<<<dim3(16, 64), 256, 0, stream>>>(Wk, WkT, 2048, 512, probe);
    tconv_kernel<<<dim3(16, 64), 256, 0, stream>>>(Wv, WvT, 2048, 512, probe);
    tconv_kernel<<<dim3(64, 64), 256, 0, stream>>>(Wq, WT,  2048, 2048, probe);

    gemm_bias_kernel<<<dim3(32, 16), 256, 0, stream>>>(Xc, WT,  bqc, Qb, 4096, 2048, 2048, nullptr);
    gemm_bias_kernel<<<dim3(32, 4),  256, 0, stream>>>(Xc, WkT, bkc, Kb, 4096, 512, 2048, nullptr);
    gemm_bias_kernel<<<dim3(32, 4),  256, 0, stream>>>(Xc, WvT, bvc, Vb, 4096, 512, 2048, nullptr);

    transpose_kernel<<<dim3(16, 128), 256, 0, stream>>>(Vb, VTb, 4096, 512);

    flash_kernel<<<dim3(32, 16, 2), 256, 0, stream>>>(Qb, Kb, VTb, OA, Ob, mlA, mlB);
    combine_kernel<<<4096, 256, 0, stream>>>(OA, Ob, mlA, mlB);

    tconv_kernel<<<dim3(64, 64), 256, 0, stream>>>(Wo, WT, 2048, 2048, probe);

    gemm_bias_kernel<<<dim3(32, 16), 256, 0, stream>>>(Ob, WT, boc, d_out, 4096, 2048, 2048, probe);
}

// Round 6
// 588.235 us; speedup vs baseline: 1.3275x; 1.3275x over previous
//
#include <hip/hip_runtime.h>
#include <math.h>

typedef unsigned short u16;
typedef __bf16 bf16_t;
typedef u16 u16x4 __attribute__((ext_vector_type(4)));
typedef u16 u16x8 __attribute__((ext_vector_type(8)));
typedef bf16_t bf16x8 __attribute__((ext_vector_type(8)));
typedef float f32x4 __attribute__((ext_vector_type(4)));

__device__ __forceinline__ float bf2f(u16 v) {
    union { unsigned u; float f; } x; x.u = ((unsigned)v) << 16; return x.f;
}
__device__ __forceinline__ u16 f2bf(float f) {
    union { float f; unsigned u; } x; x.f = f;
    unsigned u = x.u;
    return (u16)((u + 0x7fffu + ((u >> 16) & 1u)) >> 16);
}

// async global->LDS, 16B per lane; LDS dest is wave-uniform base + lane*16
__device__ __forceinline__ void glds16(const u16* g, u16* l) {
    __builtin_amdgcn_global_load_lds(
        (const __attribute__((address_space(1))) void*)g,
        (__attribute__((address_space(3))) void*)l, 16, 0, 0);
}

// ---------------------------------------------------------------------------
// Runtime dtype detector (probe = Wq). bf16: high byte of each u32 is sign/exp
// in [0x38,0x3F]; fp32: uniform mantissa byte. 64-lane majority => exact.
// ---------------------------------------------------------------------------
__device__ __forceinline__ bool is_bf16_input(const unsigned* __restrict__ probe) {
    unsigned w = probe[(threadIdx.x & 63) * 32771 + 7];
    unsigned b7 = (w >> 8) & 0x7f;
    bool hit = (b7 >= 0x38) && (b7 <= 0x3f);
    return __builtin_popcountll(__ballot(hit)) >= 32;
}

__global__ __launch_bounds__(256) void convert_kernel(
    const void* __restrict__ src, u16* __restrict__ dst, int n,
    const unsigned* __restrict__ probe)
{
    bool bf = is_bf16_input(probe);
    int i = (blockIdx.x * 256 + threadIdx.x) * 8;
    if (i >= n) return;
    if (bf) {
        *(u16x8*)&dst[i] = *(const u16x8*)&((const u16*)src)[i];
    } else {
        const float* s = (const float*)src + i;
        u16x8 o;
#pragma unroll
        for (int j = 0; j < 8; j++) o[j] = f2bf(s[j]);
        *(u16x8*)&dst[i] = o;
    }
}

// all 4 biases in one launch; dq/dk/dv MUST be adjacent (bcat layout)
__global__ __launch_bounds__(256) void convert_biases_kernel(
    const void* bq, const void* bk, const void* bv, const void* bo,
    u16* dq, u16* dk, u16* dv, u16* dob, const unsigned* __restrict__ probe)
{
    bool bf = is_bf16_input(probe);
    int i = (blockIdx.x * 256 + threadIdx.x) * 8;
    const void* s; u16* d; int off;
    if (i < 2048)      { s = bq; d = dq;  off = i; }
    else if (i < 2560) { s = bk; d = dk;  off = i - 2048; }
    else if (i < 3072) { s = bv; d = dv;  off = i - 2560; }
    else if (i < 5120) { s = bo; d = dob; off = i - 3072; }
    else return;
    if (bf) {
        *(u16x8*)&d[off] = *(const u16x8*)&((const u16*)s)[off];
    } else {
        const float* sf = (const float*)s + off;
        u16x8 o;
#pragma unroll
        for (int j = 0; j < 8; j++) o[j] = f2bf(sf[j]);
        *(u16x8*)&d[off] = o;
    }
}

__global__ __launch_bounds__(256) void tconv_kernel(
    const void* __restrict__ in, u16* __restrict__ out, int R, int C,
    const unsigned* __restrict__ probe)
{
    bool bf = is_bf16_input(probe);
    __shared__ u16 t[32][33];
    int x = threadIdx.x & 31, y = threadIdx.x >> 5;
    int bx = blockIdx.x * 32, by = blockIdx.y * 32;
    if (bf) {
        const u16* s = (const u16*)in;
#pragma unroll
        for (int i = 0; i < 32; i += 8)
            t[y + i][x] = s[(size_t)(by + y + i) * C + bx + x];
    } else {
        const float* s = (const float*)in;
#pragma unroll
        for (int i = 0; i < 32; i += 8)
            t[y + i][x] = f2bf(s[(size_t)(by + y + i) * C + bx + x]);
    }
    __syncthreads();
#pragma unroll
    for (int i = 0; i < 32; i += 8)
        out[(size_t)(bx + y + i) * R + by + x] = t[x][y + i];
}

// bf16 transpose with separate input row stride (for V slice of fused QKV)
__global__ __launch_bounds__(256) void transpose_kernel(
    const u16* __restrict__ in, u16* __restrict__ out, int R, int C, int inStride)
{
    __shared__ u16 t[32][33];
    int x = threadIdx.x & 31, y = threadIdx.x >> 5;
    int bx = blockIdx.x * 32, by = blockIdx.y * 32;
#pragma unroll
    for (int i = 0; i < 32; i += 8)
        t[y + i][x] = in[(size_t)(by + y + i) * inStride + bx + x];
    __syncthreads();
#pragma unroll
    for (int i = 0; i < 32; i += 8)
        out[(size_t)(bx + y + i) * R + by + x] = t[x][y + i];
}

// ---------------------------------------------------------------------------
// GEMM (m97 structure): C[M,N] = A[M,K] @ BT[N,K]^T + bias[N]
// LDS fragment-major; staged by global_load_lds width=16. 128x128 tile, BK=32.
// ---------------------------------------------------------------------------
__global__ __launch_bounds__(256) void gemm_bias_kernel(
    const u16* __restrict__ A, const u16* __restrict__ BT,
    const u16* __restrict__ bias, void* __restrict__ Cout,
    int M, int N, int K, const unsigned* __restrict__ probe)
{
    __shared__ __align__(16) u16 As[128 * 32];
    __shared__ __align__(16) u16 Bs[128 * 32];
    const int tid  = threadIdx.x;
    const int lane = tid & 63, wave = tid >> 6;
    const int quad = lane >> 4, li = lane & 15;
    const int bm = blockIdx.x * 128, bn = blockIdx.y * 128;
    const int wm = (wave >> 1) * 64, wn = (wave & 1) * 64;

    f32x4 acc[4][4] = {};

    const u16* Abase = &A [(size_t)(bm + lane) * K + wave * 8];
    const u16* Bbase = &BT[(size_t)(bn + lane) * K + wave * 8];
    u16* AsW = &As[(wave * 128) * 8];
    u16* BsW = &Bs[(wave * 128) * 8];

    for (int k0 = 0; k0 < K; k0 += 32) {
        glds16(Abase + k0,                  AsW);
        glds16(Abase + k0 + (size_t)64 * K, AsW + 64 * 8);
        glds16(Bbase + k0,                  BsW);
        glds16(Bbase + k0 + (size_t)64 * K, BsW + 64 * 8);
        __syncthreads();
        bf16x8 af[4], bfr[4];
#pragma unroll
        for (int i = 0; i < 4; i++)
            af[i]  = *(const bf16x8*)&As[(quad * 128 + wm + i * 16 + li) * 8];
#pragma unroll
        for (int i = 0; i < 4; i++)
            bfr[i] = *(const bf16x8*)&Bs[(quad * 128 + wn + i * 16 + li) * 8];
#pragma unroll
        for (int mt = 0; mt < 4; mt++)
#pragma unroll
            for (int nt = 0; nt < 4; nt++)
                acc[mt][nt] = __builtin_amdgcn_mfma_f32_16x16x32_bf16(
                    af[mt], bfr[nt], acc[mt][nt], 0, 0, 0);
        __syncthreads();
    }

    bool bf = probe ? is_bf16_input(probe) : true;
    if (bf) {
        u16* C16 = (u16*)Cout;
#pragma unroll
        for (int nt = 0; nt < 4; nt++) {
            int col = bn + wn + nt * 16 + li;
            float bb = bf2f(bias[col]);
#pragma unroll
            for (int mt = 0; mt < 4; mt++)
#pragma unroll
                for (int r = 0; r < 4; r++) {
                    int row = bm + wm + mt * 16 + quad * 4 + r;
                    C16[(size_t)row * N + col] = f2bf(acc[mt][nt][r] + bb);
                }
        }
    } else {
        float* Cf = (float*)Cout;
#pragma unroll
        for (int nt = 0; nt < 4; nt++) {
            int col = bn + wn + nt * 16 + li;
            float bb = bf2f(bias[col]);
#pragma unroll
            for (int mt = 0; mt < 4; mt++)
#pragma unroll
                for (int r = 0; r < 4; r++) {
                    int row = bm + wm + mt * 16 + quad * 4 + r;
                    Cf[(size_t)row * N + col] = acc[mt][nt][r] + bb;
                }
        }
    }
}

// ---------------------------------------------------------------------------
// Flash attention v5.1 (round-5 structure, K row-stride bug fixed: QRS not 512)
// QKV:[B*S, 3072] (Q cols 0..2047, K cols 2048+g*128)  VT:[512, B*S]
// O:[B*S, 2048].  Grid (S/128, H, B), 256 thr.
// ---------------------------------------------------------------------------
__global__ __launch_bounds__(256) void flash_kernel(
    const u16* __restrict__ QKV, const u16* __restrict__ VT,
    u16* __restrict__ O)
{
    constexpr int S = 2048, D = 2048, DH = 128, QRS = 3072;
    constexpr float SCALE = 0.08838834764831845f;  // 1/sqrt(128)
    __shared__ __align__(16) u16 Ks[2][32 * 136];
    __shared__ __align__(16) u16 Vt[2][128 * 40];
    __shared__ __align__(16) u16 Pw[4][32 * 40];

    const int tid  = threadIdx.x;
    const int wave = tid >> 6, lane = tid & 63;
    const int quad = lane >> 4, li = lane & 15;
    const int qt = blockIdx.x, h = blockIdx.y, b = blockIdx.z;
    const int g = h >> 2;
    const int q0w = qt * 128 + wave * 32;

    const u16* Qb = QKV + (size_t)b * S * QRS;
    const u16* Kb = QKV + (size_t)b * S * QRS + 2048 + g * DH;   // row stride QRS!
    const u16* Vg = VT + (size_t)g * DH * (2 * S) + (size_t)b * S;

    bf16x8 qf[2][4];
#pragma unroll
    for (int m = 0; m < 2; m++)
#pragma unroll
        for (int c = 0; c < 4; c++)
            qf[m][c] = *(const bf16x8*)&Qb[(size_t)(q0w + m * 16 + li) * QRS
                                           + h * DH + c * 32 + quad * 8];

    f32x4 oacc[2][8] = {};
    float mr[2] = { -INFINITY, -INFINITY };
    float lr[2] = { 0.f, 0.f };

    const int kend = qt * 128 + 128;

    // prefetch tile 0 into regs, commit to buffer 0
    u16x8 kreg[2], vreg[2];
#pragma unroll
    for (int ch = 0; ch < 2; ch++) {
        int idx = tid + ch * 256;
        kreg[ch] = *(const u16x8*)&Kb[(size_t)(idx >> 4) * QRS + (idx & 15) * 8];
        vreg[ch] = *(const u16x8*)&Vg[(size_t)(idx >> 2) * (2 * S) + (idx & 3) * 8];
    }
#pragma unroll
    for (int ch = 0; ch < 2; ch++) {
        int idx = tid + ch * 256;
        *(u16x8*)&Ks[0][(idx >> 4) * 136 + (idx & 15) * 8] = kreg[ch];
        *(u16x8*)&Vt[0][(idx >> 2) * 40  + (idx & 3) * 8]  = vreg[ch];
    }
    __syncthreads();

    int cur = 0;
    for (int kc = 0; kc < kend; kc += 32) {
        int kn = kc + 32;
        bool havenext = (kn < kend);
        if (havenext) {
#pragma unroll
            for (int ch = 0; ch < 2; ch++) {
                int idx = tid + ch * 256;
                kreg[ch] = *(const u16x8*)&Kb[(size_t)(kn + (idx >> 4)) * QRS + (idx & 15) * 8];
                vreg[ch] = *(const u16x8*)&Vg[(size_t)(idx >> 2) * (2 * S) + kn + (idx & 3) * 8];
            }
        }

        if (kc <= q0w) {
            f32x4 sacc[2][2] = {};
#pragma unroll
            for (int t = 0; t < 2; t++)
#pragma unroll
                for (int c = 0; c < 4; c++) {
                    bf16x8 kf = *(const bf16x8*)&Ks[cur][(t * 16 + li) * 136 + c * 32 + quad * 8];
#pragma unroll
                    for (int m = 0; m < 2; m++)
                        sacc[m][t] = __builtin_amdgcn_mfma_f32_16x16x32_bf16(
                            kf, qf[m][c], sacc[m][t], 0, 0, 0);
                }

            float al[2];
#pragma unroll
            for (int m = 0; m < 2; m++) {
                int row = q0w + m * 16 + li;
                f32x4 s0 = sacc[m][0] * SCALE;
                f32x4 s1 = sacc[m][1] * SCALE;
#pragma unroll
                for (int r = 0; r < 4; r++) {
                    int k0 = kc + quad * 4 + r;
                    if (k0 > row)      s0[r] = -INFINITY;
                    if (k0 + 16 > row) s1[r] = -INFINITY;
                }
                float mx = fmaxf(fmaxf(fmaxf(s0[0], s0[1]), fmaxf(s0[2], s0[3])),
                                 fmaxf(fmaxf(s1[0], s1[1]), fmaxf(s1[2], s1[3])));
                mx = fmaxf(mx, __shfl_xor(mx, 16));
                mx = fmaxf(mx, __shfl_xor(mx, 32));
                float mnew = fmaxf(mr[m], mx);
                al[m] = __expf(mr[m] - mnew);
                mr[m] = mnew;
                f32x4 p0, p1;
                float ps = 0.f;
#pragma unroll
                for (int r = 0; r < 4; r++) {
                    p0[r] = __expf(s0[r] - mnew);
                    p1[r] = __expf(s1[r] - mnew);
                    ps += p0[r] + p1[r];
                }
                ps += __shfl_xor(ps, 16);
                ps += __shfl_xor(ps, 32);
                lr[m] = lr[m] * al[m] + ps;
                u16x4 c0, c1;
#pragma unroll
                for (int r = 0; r < 4; r++) { c0[r] = f2bf(p0[r]); c1[r] = f2bf(p1[r]); }
                *(u16x4*)&Pw[wave][(m * 16 + li) * 40 + quad * 4]      = c0;
                *(u16x4*)&Pw[wave][(m * 16 + li) * 40 + 16 + quad * 4] = c1;
            }

            // rescale only if any row's max changed (rare after early tiles)
            unsigned long long need = __ballot(al[0] != 1.0f) | __ballot(al[1] != 1.0f);
            if (need) {
#pragma unroll
                for (int m = 0; m < 2; m++) {
                    float ab[4];
#pragma unroll
                    for (int r = 0; r < 4; r++)
                        ab[r] = __shfl(al[m], quad * 4 + r, 16);
#pragma unroll
                    for (int dt = 0; dt < 8; dt++)
#pragma unroll
                        for (int r = 0; r < 4; r++)
                            oacc[m][dt][r] *= ab[r];
                }
            }

            asm volatile("s_waitcnt lgkmcnt(0)" ::: "memory");
            union { u16x8 u; bf16x8 bv; } pc0, pc1;
            pc0.u = *(const u16x8*)&Pw[wave][(0 * 16 + li) * 40 + quad * 8];
            pc1.u = *(const u16x8*)&Pw[wave][(1 * 16 + li) * 40 + quad * 8];
            bf16x8 pf[2] = { pc0.bv, pc1.bv };

#pragma unroll
            for (int dt = 0; dt < 8; dt++) {
                bf16x8 vf = *(const bf16x8*)&Vt[cur][(dt * 16 + li) * 40 + quad * 8];
#pragma unroll
                for (int m = 0; m < 2; m++)
                    oacc[m][dt] = __builtin_amdgcn_mfma_f32_16x16x32_bf16(
                        pf[m], vf, oacc[m][dt], 0, 0, 0);
            }
        }

        // commit next tile into the other buffer
        if (havenext) {
#pragma unroll
            for (int ch = 0; ch < 2; ch++) {
                int idx = tid + ch * 256;
                *(u16x8*)&Ks[cur ^ 1][(idx >> 4) * 136 + (idx & 15) * 8] = kreg[ch];
                *(u16x8*)&Vt[cur ^ 1][(idx >> 2) * 40  + (idx & 3) * 8]  = vreg[ch];
            }
        }
        __syncthreads();
        cur ^= 1;
    }

    u16* Ob = O + (size_t)b * S * D;
#pragma unroll
    for (int m = 0; m < 2; m++) {
#pragma unroll
        for (int r = 0; r < 4; r++) {
            float linv = 1.0f / __shfl(lr[m], quad * 4 + r, 16);
            int row = q0w + m * 16 + quad * 4 + r;
#pragma unroll
            for (int dt = 0; dt < 8; dt++)
                Ob[(size_t)row * D + h * DH + dt * 16 + li] = f2bf(oacc[m][dt][r] * linv);
        }
    }
}

// ---------------------------------------------------------------------------
extern "C" void kernel_launch(void* const* d_in, const int* in_sizes, int n_in,
                              void* d_out, int out_size, void* d_ws, size_t ws_size,
                              hipStream_t stream)
{
    const void* X  = d_in[0];
    const void* Wq = d_in[3];
    const void* bq = d_in[4];
    const void* Wk = d_in[5];
    const void* bk = d_in[6];
    const void* Wv = d_in[7];
    const void* bv = d_in[8];
    const void* Wo = d_in[9];
    const void* bo = d_in[10];
    const unsigned* probe = (const unsigned*)d_in[3];

    u16* ws    = (u16*)d_ws;
    u16* Xc    = ws;                      // [4096][2048]; reused as Ob after QKV GEMM
    u16* WcatT = Xc + 8388608;            // [3072][2048] (WqT|WkT|WvT); reused as WoT
    u16* bqc   = WcatT + 6291456;         // 2048 | 512 | 512 adjacent = bcat[3072]
    u16* bkc   = bqc + 2048;
    u16* bvc   = bkc + 512;
    u16* boc   = bvc + 512;
    u16* QKVb  = boc + 2048;              // [4096][3072]
    u16* VTb   = QKVb + 12582912;         // [512][4096]
    u16* Ob    = Xc;                      // overlay (Xc dead after QKV GEMM)
    u16* WoT   = WcatT;                   // overlay (WcatT dead after QKV GEMM)

    convert_kernel<<<4096, 256, 0, stream>>>(X, Xc, 8388608, probe);
    convert_biases_kernel<<<3, 256, 0, stream>>>(bq, bk, bv, bo, bqc, bkc, bvc, boc, probe);

    // W^T concat: rows [0,2048)=WqT, [2048,2560)=WkT, [2560,3072)=WvT
    tconv_kernel<<<dim3(64, 64), 256, 0, stream>>>(Wq, WcatT,                  2048, 2048, probe);
    tconv_kernel<<<dim3(16, 64), 256, 0, stream>>>(Wk, WcatT + 2048 * 2048,    2048, 512,  probe);
    tconv_kernel<<<dim3(16, 64), 256, 0, stream>>>(Wv, WcatT + 2560 * 2048,    2048, 512,  probe);

    // fused QKV projection: [4096][3072]
    gemm_bias_kernel<<<dim3(32, 24), 256, 0, stream>>>(Xc, WcatT, bqc, QKVb, 4096, 3072, 2048, nullptr);

    // V^T: [512][4096] from QKV cols [2560,3072)
    transpose_kernel<<<dim3(16, 128), 256, 0, stream>>>(QKVb + 2560, VTb, 4096, 512, 3072);

    // WoT can now overwrite WcatT
    tconv_kernel<<<dim3(64, 64), 256, 0, stream>>>(Wo, WoT, 2048, 2048, probe);

    flash_kernel<<<dim3(16, 16, 2), 256, 0, stream>>>(QKVb, VTb, Ob);

    gemm_bias_kernel<<<dim3(32, 16), 256, 0, stream>>>(Ob, WoT, boc, d_out, 4096, 2048, 2048, probe);
}

// Round 8
// 563.422 us; speedup vs baseline: 1.3860x; 1.0440x over previous
//
#include <hip/hip_runtime.h>

typedef unsigned short u16;
typedef __bf16 bf16_t;
typedef u16 u16x4 __attribute__((ext_vector_type(4)));
typedef u16 u16x8 __attribute__((ext_vector_type(8)));
typedef bf16_t bf16x8 __attribute__((ext_vector_type(8)));
typedef float f32x4 __attribute__((ext_vector_type(4)));

#define NEG_INF (-__builtin_inff())

__device__ __forceinline__ float bf2f(u16 v) {
    union { unsigned u; float f; } x; x.u = ((unsigned)v) << 16; return x.f;
}
__device__ __forceinline__ u16 f2bf(float f) {
    union { float f; unsigned u; } x; x.f = f;
    unsigned u = x.u;
    return (u16)((u + 0x7fffu + ((u >> 16) & 1u)) >> 16);
}
__device__ __forceinline__ float exp2f_fast(float x) {
    return __builtin_amdgcn_exp2f(x);   // v_exp_f32: 2^x
}

// async global->LDS, 16B per lane; LDS dest is wave-uniform base + lane*16
__device__ __forceinline__ void glds16(const u16* g, u16* l) {
    __builtin_amdgcn_global_load_lds(
        (const __attribute__((address_space(1))) void*)g,
        (__attribute__((address_space(3))) void*)l, 16, 0, 0);
}

// ---------------------------------------------------------------------------
// Runtime dtype detector (probe = Wq). bf16: high byte of each u32 is sign/exp
// in [0x38,0x3F]; fp32: uniform mantissa byte. 64-lane majority => exact.
// ---------------------------------------------------------------------------
__device__ __forceinline__ bool is_bf16_input(const unsigned* __restrict__ probe) {
    unsigned w = probe[(threadIdx.x & 63) * 32771 + 7];
    unsigned b7 = (w >> 8) & 0x7f;
    bool hit = (b7 >= 0x38) && (b7 <= 0x3f);
    return __builtin_popcountll(__ballot(hit)) >= 32;
}

__global__ __launch_bounds__(256) void convert_kernel(
    const void* __restrict__ src, u16* __restrict__ dst, int n,
    const unsigned* __restrict__ probe)
{
    bool bf = is_bf16_input(probe);
    int i = (blockIdx.x * 256 + threadIdx.x) * 8;
    if (i >= n) return;
    if (bf) {
        *(u16x8*)&dst[i] = *(const u16x8*)&((const u16*)src)[i];
    } else {
        const float* s = (const float*)src + i;
        u16x8 o;
#pragma unroll
        for (int j = 0; j < 8; j++) o[j] = f2bf(s[j]);
        *(u16x8*)&dst[i] = o;
    }
}

// all 4 biases in one launch; dq/dk/dv MUST be adjacent (bcat layout)
__global__ __launch_bounds__(256) void convert_biases_kernel(
    const void* bq, const void* bk, const void* bv, const void* bo,
    u16* dq, u16* dk, u16* dv, u16* dob, const unsigned* __restrict__ probe)
{
    bool bf = is_bf16_input(probe);
    int i = (blockIdx.x * 256 + threadIdx.x) * 8;
    const void* s; u16* d; int off;
    if (i < 2048)      { s = bq; d = dq;  off = i; }
    else if (i < 2560) { s = bk; d = dk;  off = i - 2048; }
    else if (i < 3072) { s = bv; d = dv;  off = i - 2560; }
    else if (i < 5120) { s = bo; d = dob; off = i - 3072; }
    else return;
    if (bf) {
        *(u16x8*)&d[off] = *(const u16x8*)&((const u16*)s)[off];
    } else {
        const float* sf = (const float*)s + off;
        u16x8 o;
#pragma unroll
        for (int j = 0; j < 8; j++) o[j] = f2bf(sf[j]);
        *(u16x8*)&d[off] = o;
    }
}

__global__ __launch_bounds__(256) void tconv_kernel(
    const void* __restrict__ in, u16* __restrict__ out, int R, int C,
    const unsigned* __restrict__ probe)
{
    bool bf = is_bf16_input(probe);
    __shared__ u16 t[32][33];
    int x = threadIdx.x & 31, y = threadIdx.x >> 5;
    int bx = blockIdx.x * 32, by = blockIdx.y * 32;
    if (bf) {
        const u16* s = (const u16*)in;
#pragma unroll
        for (int i = 0; i < 32; i += 8)
            t[y + i][x] = s[(size_t)(by + y + i) * C + bx + x];
    } else {
        const float* s = (const float*)in;
#pragma unroll
        for (int i = 0; i < 32; i += 8)
            t[y + i][x] = f2bf(s[(size_t)(by + y + i) * C + bx + x]);
    }
    __syncthreads();
#pragma unroll
    for (int i = 0; i < 32; i += 8)
        out[(size_t)(bx + y + i) * R + by + x] = t[x][y + i];
}

// bf16 transpose with separate input row stride (for V slice of fused QKV)
__global__ __launch_bounds__(256) void transpose_kernel(
    const u16* __restrict__ in, u16* __restrict__ out, int R, int C, int inStride)
{
    __shared__ u16 t[32][33];
    int x = threadIdx.x & 31, y = threadIdx.x >> 5;
    int bx = blockIdx.x * 32, by = blockIdx.y * 32;
#pragma unroll
    for (int i = 0; i < 32; i += 8)
        t[y + i][x] = in[(size_t)(by + y + i) * inStride + bx + x];
    __syncthreads();
#pragma unroll
    for (int i = 0; i < 32; i += 8)
        out[(size_t)(bx + y + i) * R + by + x] = t[x][y + i];
}

// ---------------------------------------------------------------------------
// GEMM (m97 structure): C[M,N] = A[M,K] @ BT[N,K]^T + bias[N]
// LDS fragment-major; staged by global_load_lds width=16. 128x128 tile, BK=32.
// ---------------------------------------------------------------------------
__global__ __launch_bounds__(256) void gemm_bias_kernel(
    const u16* __restrict__ A, const u16* __restrict__ BT,
    const u16* __restrict__ bias, void* __restrict__ Cout,
    int M, int N, int K, const unsigned* __restrict__ probe)
{
    __shared__ __align__(16) u16 As[128 * 32];
    __shared__ __align__(16) u16 Bs[128 * 32];
    const int tid  = threadIdx.x;
    const int lane = tid & 63, wave = tid >> 6;
    const int quad = lane >> 4, li = lane & 15;
    const int bm = blockIdx.x * 128, bn = blockIdx.y * 128;
    const int wm = (wave >> 1) * 64, wn = (wave & 1) * 64;

    f32x4 acc[4][4] = {};

    const u16* Abase = &A [(size_t)(bm + lane) * K + wave * 8];
    const u16* Bbase = &BT[(size_t)(bn + lane) * K + wave * 8];
    u16* AsW = &As[(wave * 128) * 8];
    u16* BsW = &Bs[(wave * 128) * 8];

    for (int k0 = 0; k0 < K; k0 += 32) {
        glds16(Abase + k0,                  AsW);
        glds16(Abase + k0 + (size_t)64 * K, AsW + 64 * 8);
        glds16(Bbase + k0,                  BsW);
        glds16(Bbase + k0 + (size_t)64 * K, BsW + 64 * 8);
        __syncthreads();
        bf16x8 af[4], bfr[4];
#pragma unroll
        for (int i = 0; i < 4; i++)
            af[i]  = *(const bf16x8*)&As[(quad * 128 + wm + i * 16 + li) * 8];
#pragma unroll
        for (int i = 0; i < 4; i++)
            bfr[i] = *(const bf16x8*)&Bs[(quad * 128 + wn + i * 16 + li) * 8];
#pragma unroll
        for (int mt = 0; mt < 4; mt++)
#pragma unroll
            for (int nt = 0; nt < 4; nt++)
                acc[mt][nt] = __builtin_amdgcn_mfma_f32_16x16x32_bf16(
                    af[mt], bfr[nt], acc[mt][nt], 0, 0, 0);
        __syncthreads();
    }

    bool bf = probe ? is_bf16_input(probe) : true;
    if (bf) {
        u16* C16 = (u16*)Cout;
#pragma unroll
        for (int nt = 0; nt < 4; nt++) {
            int col = bn + wn + nt * 16 + li;
            float bb = bf2f(bias[col]);
#pragma unroll
            for (int mt = 0; mt < 4; mt++)
#pragma unroll
                for (int r = 0; r < 4; r++) {
                    int row = bm + wm + mt * 16 + quad * 4 + r;
                    C16[(size_t)row * N + col] = f2bf(acc[mt][nt][r] + bb);
                }
        }
    } else {
        float* Cf = (float*)Cout;
#pragma unroll
        for (int nt = 0; nt < 4; nt++) {
            int col = bn + wn + nt * 16 + li;
            float bb = bf2f(bias[col]);
#pragma unroll
            for (int mt = 0; mt < 4; mt++)
#pragma unroll
                for (int r = 0; r < 4; r++) {
                    int row = bm + wm + mt * 16 + quad * 4 + r;
                    Cf[(size_t)row * N + col] = acc[mt][nt][r] + bb;
                }
        }
    }
}

// ---------------------------------------------------------------------------
// Flash attention v7: round-3 two-barrier loop (max prefetch slack), 64-row
// Q-tile, 2 waves x 32 rows, 128 thr, grid (32,16,2)=1024 blocks (4/CU).
// Base-2 softmax with Q pre-scaled by 1/sqrt(dh)*log2(e); mask only on the
// single tile where kc==q0w (both are multiples of 32).
// QKV:[B*S,3072] (Q cols 0..2047, K cols 2048+g*128)  VT:[512,B*S]  O:[B*S,2048]
// ---------------------------------------------------------------------------
__global__ __launch_bounds__(128) void flash_kernel(
    const u16* __restrict__ QKV, const u16* __restrict__ VT,
    u16* __restrict__ O)
{
    constexpr int S = 2048, D = 2048, DH = 128, QRS = 3072;
    constexpr float QSCALE = 0.12751791881931264f;  // 1/sqrt(128)*log2(e)
    __shared__ __align__(16) u16 Ks[32 * 136];   //  8704 B
    __shared__ __align__(16) u16 Vt[128 * 40];   // 10240 B
    __shared__ __align__(16) u16 Pw[2][32 * 40]; //  5120 B

    const int tid  = threadIdx.x;
    const int wave = tid >> 6, lane = tid & 63;
    const int quad = lane >> 4, li = lane & 15;
    const int qt = blockIdx.x, h = blockIdx.y, b = blockIdx.z;
    const int g = h >> 2;
    const int q0w = qt * 64 + wave * 32;

    const u16* Qb = QKV + (size_t)b * S * QRS;
    const u16* Kb = QKV + (size_t)b * S * QRS + 2048 + g * DH;
    const u16* Vg = VT + (size_t)g * DH * (2 * S) + (size_t)b * S;

    // Q fragments, pre-scaled by QSCALE (folds softmax scale + log2e)
    bf16x8 qf[2][4];
#pragma unroll
    for (int m = 0; m < 2; m++)
#pragma unroll
        for (int c = 0; c < 4; c++) {
            union { u16x8 u; bf16x8 bv; } q;
            q.u = *(const u16x8*)&Qb[(size_t)(q0w + m * 16 + li) * QRS
                                     + h * DH + c * 32 + quad * 8];
#pragma unroll
            for (int j = 0; j < 8; j++) q.u[j] = f2bf(bf2f(q.u[j]) * QSCALE);
            qf[m][c] = q.bv;
        }

    f32x4 oacc[2][8] = {};
    float mr[2] = { NEG_INF, NEG_INF };
    float lr[2] = { 0.f, 0.f };

    const int kend = qt * 64 + 64;

    // prefetch tile 0 into regs
    u16x8 kreg[4], vreg[4];
#pragma unroll
    for (int ch = 0; ch < 4; ch++) {
        int idx = tid + ch * 128;
        kreg[ch] = *(const u16x8*)&Kb[(size_t)(idx >> 4) * QRS + (idx & 15) * 8];
        vreg[ch] = *(const u16x8*)&Vg[(size_t)(idx >> 2) * (2 * S) + (idx & 3) * 8];
    }

    for (int kc = 0; kc < kend; kc += 32) {
        // commit prefetched tile to LDS (loads were issued >=1 iteration ago)
#pragma unroll
        for (int ch = 0; ch < 4; ch++) {
            int idx = tid + ch * 128;
            *(u16x8*)&Ks[(idx >> 4) * 136 + (idx & 15) * 8] = kreg[ch];
            *(u16x8*)&Vt[(idx >> 2) * 40  + (idx & 3) * 8]  = vreg[ch];
        }
        __syncthreads();

        // issue prefetch for next tile (consumed at next iteration's commit)
        int kn = kc + 32;
        if (kn < kend) {
#pragma unroll
            for (int ch = 0; ch < 4; ch++) {
                int idx = tid + ch * 128;
                kreg[ch] = *(const u16x8*)&Kb[(size_t)(kn + (idx >> 4)) * QRS + (idx & 15) * 8];
                vreg[ch] = *(const u16x8*)&Vg[(size_t)(idx >> 2) * (2 * S) + kn + (idx & 3) * 8];
            }
        }

        if (kc <= q0w) {
            // S^T = K . Q^T : lane holds 4 contiguous keys (quad*4+r) of q-row li
            f32x4 sacc[2][2] = {};
#pragma unroll
            for (int t = 0; t < 2; t++)
#pragma unroll
                for (int c = 0; c < 4; c++) {
                    bf16x8 kf = *(const bf16x8*)&Ks[(t * 16 + li) * 136 + c * 32 + quad * 8];
#pragma unroll
                    for (int m = 0; m < 2; m++)
                        sacc[m][t] = __builtin_amdgcn_mfma_f32_16x16x32_bf16(
                            kf, qf[m][c], sacc[m][t], 0, 0, 0);
                }

            const bool domask = (kc == q0w);   // only tile with any masked pair
            float al[2];
#pragma unroll
            for (int m = 0; m < 2; m++) {
                int row = q0w + m * 16 + li;
                f32x4 s0 = sacc[m][0];
                f32x4 s1 = sacc[m][1];
                if (domask) {
#pragma unroll
                    for (int r = 0; r < 4; r++) {
                        int k0 = kc + quad * 4 + r;
                        if (k0 > row)      s0[r] = NEG_INF;
                        if (k0 + 16 > row) s1[r] = NEG_INF;
                    }
                }
                float mx = fmaxf(fmaxf(fmaxf(s0[0], s0[1]), fmaxf(s0[2], s0[3])),
                                 fmaxf(fmaxf(s1[0], s1[1]), fmaxf(s1[2], s1[3])));
                mx = fmaxf(mx, __shfl_xor(mx, 16));
                mx = fmaxf(mx, __shfl_xor(mx, 32));
                float mnew = fmaxf(mr[m], mx);
                al[m] = exp2f_fast(mr[m] - mnew);
                mr[m] = mnew;
                f32x4 p0, p1;
                float ps = 0.f;
#pragma unroll
                for (int r = 0; r < 4; r++) {
                    p0[r] = exp2f_fast(s0[r] - mnew);
                    p1[r] = exp2f_fast(s1[r] - mnew);
                    ps += p0[r] + p1[r];
                }
                ps += __shfl_xor(ps, 16);
                ps += __shfl_xor(ps, 32);
                lr[m] = lr[m] * al[m] + ps;
                u16x4 c0, c1;
#pragma unroll
                for (int r = 0; r < 4; r++) { c0[r] = f2bf(p0[r]); c1[r] = f2bf(p1[r]); }
                *(u16x4*)&Pw[wave][(m * 16 + li) * 40 + quad * 4]      = c0;
                *(u16x4*)&Pw[wave][(m * 16 + li) * 40 + 16 + quad * 4] = c1;
            }

            // rescale only if any row's max changed
            unsigned long long need = __ballot(al[0] != 1.0f) | __ballot(al[1] != 1.0f);
            if (need) {
#pragma unroll
                for (int m = 0; m < 2; m++) {
                    float ab[4];
#pragma unroll
                    for (int r = 0; r < 4; r++)
                        ab[r] = __shfl(al[m], quad * 4 + r, 16);
#pragma unroll
                    for (int dt = 0; dt < 8; dt++)
#pragma unroll
                        for (int r = 0; r < 4; r++)
                            oacc[m][dt][r] *= ab[r];
                }
            }

            asm volatile("s_waitcnt lgkmcnt(0)" ::: "memory");
            union { u16x8 u; bf16x8 bv; } pc0, pc1;
            pc0.u = *(const u16x8*)&Pw[wave][(0 * 16 + li) * 40 + quad * 8];
            pc1.u = *(const u16x8*)&Pw[wave][(1 * 16 + li) * 40 + quad * 8];
            bf16x8 pf[2] = { pc0.bv, pc1.bv };

#pragma unroll
            for (int dt = 0; dt < 8; dt++) {
                bf16x8 vf = *(const bf16x8*)&Vt[(dt * 16 + li) * 40 + quad * 8];
#pragma unroll
                for (int m = 0; m < 2; m++)
                    oacc[m][dt] = __builtin_amdgcn_mfma_f32_16x16x32_bf16(
                        pf[m], vf, oacc[m][dt], 0, 0, 0);
            }
        }
        __syncthreads();
    }

    u16* Ob = O + (size_t)b * S * D;
#pragma unroll
    for (int m = 0; m < 2; m++) {
#pragma unroll
        for (int r = 0; r < 4; r++) {
            float linv = 1.0f / __shfl(lr[m], quad * 4 + r, 16);
            int row = q0w + m * 16 + quad * 4 + r;
#pragma unroll
            for (int dt = 0; dt < 8; dt++)
                Ob[(size_t)row * D + h * DH + dt * 16 + li] = f2bf(oacc[m][dt][r] * linv);
        }
    }
}

// ---------------------------------------------------------------------------
extern "C" void kernel_launch(void* const* d_in, const int* in_sizes, int n_in,
                              void* d_out, int out_size, void* d_ws, size_t ws_size,
                              hipStream_t stream)
{
    const void* X  = d_in[0];
    const void* Wq = d_in[3];
    const void* bq = d_in[4];
    const void* Wk = d_in[5];
    const void* bk = d_in[6];
    const void* Wv = d_in[7];
    const void* bv = d_in[8];
    const void* Wo = d_in[9];
    const void* bo = d_in[10];
    const unsigned* probe = (const unsigned*)d_in[3];

    u16* ws    = (u16*)d_ws;
    u16* Xc    = ws;                      // [4096][2048]; reused as Ob after QKV GEMM
    u16* WcatT = Xc + 8388608;            // [3072][2048] (WqT|WkT|WvT); reused as WoT
    u16* bqc   = WcatT + 6291456;         // 2048 | 512 | 512 adjacent = bcat[3072]
    u16* bkc   = bqc + 2048;
    u16* bvc   = bkc + 512;
    u16* boc   = bvc + 512;
    u16* QKVb  = boc + 2048;              // [4096][3072]
    u16* VTb   = QKVb + 12582912;         // [512][4096]
    u16* Ob    = Xc;                      // overlay (Xc dead after QKV GEMM)
    u16* WoT   = WcatT;                   // overlay (WcatT dead after QKV GEMM)

    convert_kernel<<<4096, 256, 0, stream>>>(X, Xc, 8388608, probe);
    convert_biases_kernel<<<3, 256, 0, stream>>>(bq, bk, bv, bo, bqc, bkc, bvc, boc, probe);

    // W^T concat: rows [0,2048)=WqT, [2048,2560)=WkT, [2560,3072)=WvT
    tconv_kernel<<<dim3(64, 64), 256, 0, stream>>>(Wq, WcatT,                  2048, 2048, probe);
    tconv_kernel<<<dim3(16, 64), 256, 0, stream>>>(Wk, WcatT + 2048 * 2048,    2048, 512,  probe);
    tconv_kernel<<<dim3(16, 64), 256, 0, stream>>>(Wv, WcatT + 2560 * 2048,    2048, 512,  probe);

    // fused QKV projection: [4096][3072]
    gemm_bias_kernel<<<dim3(32, 24), 256, 0, stream>>>(Xc, WcatT, bqc, QKVb, 4096, 3072, 2048, nullptr);

    // V^T: [512][4096] from QKV cols [2560,3072)
    transpose_kernel<<<dim3(16, 128), 256, 0, stream>>>(QKVb + 2560, VTb, 4096, 512, 3072);

    // WoT can now overwrite WcatT
    tconv_kernel<<<dim3(64, 64), 256, 0, stream>>>(Wo, WoT, 2048, 2048, probe);

    flash_kernel<<<dim3(32, 16, 2), 128, 0, stream>>>(QKVb, VTb, Ob);

    gemm_bias_kernel<<<dim3(32, 16), 256, 0, stream>>>(Ob, WoT, boc, d_out, 4096, 2048, 2048, probe);
}